// Round 9
// baseline (223.043 us; speedup 1.0000x reference)
//
#include <hip/hip_runtime.h>
#include <hip/hip_bf16.h>
#include <math.h>
#include <stdint.h>

#define D_MODEL 1024
#define NHEADS  16
#define NKV     4
#define HD      64
#define SEQ     2048
#define BATCH   4
#define MTOK    (BATCH*SEQ)            // 8192 tokens
#define NQKV    (D_MODEL + 2*NKV*HD)   // 1536
#define ASCALE  0.125f
#define CAP     30.0f

using f32x4  = __attribute__((ext_vector_type(4))) float;
using f32x2  = __attribute__((ext_vector_type(2))) float;
using bf16x8 = __attribute__((ext_vector_type(8))) short;
using u32x4  = __attribute__((ext_vector_type(4))) unsigned int;

__device__ __forceinline__ unsigned short f2bf(float f) {
  union { float f; unsigned u; } v; v.f = f;
  unsigned u = v.u + 0x7fffu + ((v.u >> 16) & 1u);
  return (unsigned short)(u >> 16);
}
__device__ __forceinline__ unsigned short f2bf_hup(float f) {  // round-half-up
  union { float f; unsigned u; } v; v.f = f;
  return (unsigned short)((v.u + 0x8000u) >> 16);
}
__device__ __forceinline__ float fexp2(float x) {   // raw v_exp_f32
  return __builtin_amdgcn_exp2f(x);
}
__device__ __forceinline__ void async_copy16(void* lds, const void* g) {
  __builtin_amdgcn_global_load_lds(
      (const __attribute__((address_space(1))) unsigned int*)(uintptr_t)g,
      (__attribute__((address_space(3))) unsigned int*)(uintptr_t)lds, 16, 0, 0);
}

// ---------------- fused fp32 -> bf16 convert for all 5 inputs ----------------
__global__ __launch_bounds__(256) void cvt_all(
    const float* __restrict__ x, const float* __restrict__ wq,
    const float* __restrict__ wk, const float* __restrict__ wv,
    const float* __restrict__ wo,
    unsigned short* __restrict__ xb, unsigned short* __restrict__ wqkv,
    unsigned short* __restrict__ wob) {
  const long i = (long)(blockIdx.x * 256 + threadIdx.x) * 4;
  const float* src; unsigned short* dst; long off;
  if (i < 8388608L)      { src = x;  dst = xb;             off = i; }
  else if (i < 9437184L) { src = wq; dst = wqkv;           off = i - 8388608L; }
  else if (i < 9699328L) { src = wk; dst = wqkv + 1048576; off = i - 9437184L; }
  else if (i < 9961472L) { src = wv; dst = wqkv + 1310720; off = i - 9699328L; }
  else                   { src = wo; dst = wob;            off = i - 9961472L; }
  float4 v = *(const float4*)(src + off);
  ushort4 o; o.x = f2bf(v.x); o.y = f2bf(v.y); o.z = f2bf(v.z); o.w = f2bf(v.w);
  *(ushort4*)(dst + off) = o;
}

// ---------------- QKV GEMM, 128x64 tile, fused RMSNorm + RoPE epilogue --------
// R13: co-residency lever. m102's shape curve shows 128²-2ph throughput is
// governed by blocks/CU (1/CU=320 TF, 4/CU=912); our 128² grids sat at 3/CU
// (qkv) and 2/CU (bt) ≈ 400-430 TF. 128x64 tile: LDS 24KB -> 6 blocks/CU
// (qkv grid 1536 = 6/CU, bt 1024 = 4/CU). Wave w owns rows [32w,32w+32) x
// all 64 cols (acc[2][4]) so each wave still holds the FULL head width and
// the RMSNorm/RoPE epilogue is unchanged (hs = nb). Skeleton = R8 sync-dbuf
// (measured best; counted-vmcnt/XCD-remap/fused-cvt all measured <= 0).
__global__ __launch_bounds__(256) void gemm_qkv(
    const unsigned short* __restrict__ A, const unsigned short* __restrict__ B,
    const float* __restrict__ qw, const float* __restrict__ kw,
    unsigned short* __restrict__ Qn, unsigned short* __restrict__ Kn,
    unsigned short* __restrict__ Vt) {
  __shared__ __align__(16) unsigned short As[2][128 * 32];   // 2 x 8 KB
  __shared__ __align__(16) unsigned short Bs[2][64 * 32];    // 2 x 4 KB
  const int t = threadIdx.x;
  const int w = t >> 6, l = t & 63;
  const int mb = blockIdx.x, nb = blockIdx.y;
  const int quad = l >> 4, ln = l & 15;
  const int K = D_MODEL;
  f32x4 acc[2][4] = {};
  const unsigned short* Ag = A + (size_t)(mb * 128 + w * 32) * K;   // wave's 32-row slab
  const unsigned short* Bg = B + (size_t)(nb * 64 + (t >> 2)) * K;  // B row per thread
  const int lrow = l >> 2, lcol = (l & 3) * 8;
  const int awo = w * 2048 + l * 16;             // A-tile byte slot (wave slab)
  const int bwo = t * 16;                        // B-tile byte slot (linear 4KB)
  const int bcol = (t & 3) * 8;

  // prologue: stage kb=0 into buffer 0
  async_copy16((char*)As[0] + awo,        Ag + (size_t)lrow * K + lcol);
  async_copy16((char*)As[0] + awo + 1024, Ag + (size_t)(16 + lrow) * K + lcol);
  async_copy16((char*)Bs[0] + bwo,        Bg + bcol);

  int cur = 0;
  for (int kb = 0; kb < K; kb += 32) {
    __syncthreads();   // drains vmcnt: buf[cur] staged; prior reads of buf^1 done
    if (kb + 32 < K) {
      const int kn = kb + 32;
      async_copy16((char*)As[cur ^ 1] + awo,        Ag + (size_t)lrow * K + kn + lcol);
      async_copy16((char*)As[cur ^ 1] + awo + 1024, Ag + (size_t)(16 + lrow) * K + kn + lcol);
      async_copy16((char*)Bs[cur ^ 1] + bwo,        Bg + kn + bcol);
    }
    bf16x8 af[2], bfr[4];
#pragma unroll
    for (int mt = 0; mt < 2; ++mt)
      af[mt] = *(const bf16x8*)(As[cur] + (w * 32 + mt * 16 + ln) * 32 + quad * 8);
#pragma unroll
    for (int nt = 0; nt < 4; ++nt)
      bfr[nt] = *(const bf16x8*)(Bs[cur] + (nt * 16 + ln) * 32 + quad * 8);
#pragma unroll
    for (int mt = 0; mt < 2; ++mt)
#pragma unroll
      for (int nt = 0; nt < 4; ++nt)
        acc[mt][nt] = __builtin_amdgcn_mfma_f32_16x16x32_bf16(af[mt], bfr[nt], acc[mt][nt], 0, 0, 0);
    cur ^= 1;
  }

  const int hs = nb;                             // head slot 0..23
  const int bB = mb >> 4;
  const int sBase = ((mb & 15) * 128) + w * 32;

  if (hs < 20) {
    const float* wgt = (hs < 16) ? qw : kw;
    float wv_[4];
#pragma unroll
    for (int nt = 0; nt < 4; ++nt) wv_[nt] = wgt[nt * 16 + ln];
    const float f0 = __expf(-(float)ln * 0.2878231366f);   // ln(10000)/32
    const float f1 = f0 * 0.01f;
    unsigned short* dst = (hs < 16)
        ? Qn + (size_t)(bB * 16 + hs) * SEQ * 64
        : Kn + (size_t)(bB * 4 + (hs - 16)) * SEQ * 64;
#pragma unroll
    for (int mt = 0; mt < 2; ++mt) {
#pragma unroll
      for (int r = 0; r < 4; ++r) {
        const int sTok = sBase + mt * 16 + quad * 4 + r;
        float ss = 0.f;
#pragma unroll
        for (int nt = 0; nt < 4; ++nt) ss = fmaf(acc[mt][nt][r], acc[mt][nt][r], ss);
        ss += __shfl_xor(ss, 1, 64); ss += __shfl_xor(ss, 2, 64);
        ss += __shfl_xor(ss, 4, 64); ss += __shfl_xor(ss, 8, 64);
        const float inv = rsqrtf(ss * (1.0f / 64.0f) + 1e-6f);
        float xn[4];
#pragma unroll
        for (int nt = 0; nt < 4; ++nt) xn[nt] = acc[mt][nt][r] * inv * wv_[nt];
        float sn0, cs0, sn1, cs1;
        __sincosf((float)sTok * f0, &sn0, &cs0);
        __sincosf((float)sTok * f1, &sn1, &cs1);
        const float o0 = xn[0] * cs0 - xn[2] * sn0;
        const float o1 = xn[1] * cs1 - xn[3] * sn1;
        const float o2 = xn[2] * cs0 + xn[0] * sn0;
        const float o3 = xn[3] * cs1 + xn[1] * sn1;
        const size_t ro = (size_t)sTok * 64 + ln;
        dst[ro]      = f2bf(o0);
        dst[ro + 16] = f2bf(o1);
        dst[ro + 32] = f2bf(o2);
        dst[ro + 48] = f2bf(o3);
      }
    }
  } else {
    unsigned short* dst = Vt + (size_t)(bB * 4 + (hs - 20)) * 64 * SEQ;
#pragma unroll
    for (int mt = 0; mt < 2; ++mt)
#pragma unroll
      for (int nt = 0; nt < 4; ++nt)
#pragma unroll
        for (int r = 0; r < 4; ++r) {
          const int sTok = sBase + mt * 16 + quad * 4 + r;
          dst[(size_t)(nt * 16 + ln) * SEQ + sTok] = f2bf(acc[mt][nt][r]);
        }
  }
}

// ---------------- GEMM: C[M,N] f32 = A[M,K]bf16 * B[N,K]bf16^T ----------------
// R13: same 128x64 geometry (grid 64x16 = 1024 blocks = 4/CU, LDS 24KB).
__global__ __launch_bounds__(256) void gemm_bt_f32(
    const unsigned short* __restrict__ A, const unsigned short* __restrict__ B,
    float* __restrict__ C, int M, int N, int K) {
  __shared__ __align__(16) unsigned short As[2][128 * 32];
  __shared__ __align__(16) unsigned short Bs[2][64 * 32];
  const int t = threadIdx.x;
  const int w = t >> 6, l = t & 63;
  const int mb = blockIdx.x, nb = blockIdx.y;
  const int quad = l >> 4, ln = l & 15;
  f32x4 acc[2][4] = {};
  const unsigned short* Ag = A + (size_t)(mb * 128 + w * 32) * K;
  const unsigned short* Bg = B + (size_t)(nb * 64 + (t >> 2)) * K;
  const int lrow = l >> 2, lcol = (l & 3) * 8;
  const int awo = w * 2048 + l * 16;
  const int bwo = t * 16;
  const int bcol = (t & 3) * 8;

  async_copy16((char*)As[0] + awo,        Ag + (size_t)lrow * K + lcol);
  async_copy16((char*)As[0] + awo + 1024, Ag + (size_t)(16 + lrow) * K + lcol);
  async_copy16((char*)Bs[0] + bwo,        Bg + bcol);

  int cur = 0;
  for (int kb = 0; kb < K; kb += 32) {
    __syncthreads();
    if (kb + 32 < K) {
      const int kn = kb + 32;
      async_copy16((char*)As[cur ^ 1] + awo,        Ag + (size_t)lrow * K + kn + lcol);
      async_copy16((char*)As[cur ^ 1] + awo + 1024, Ag + (size_t)(16 + lrow) * K + kn + lcol);
      async_copy16((char*)Bs[cur ^ 1] + bwo,        Bg + kn + bcol);
    }
    bf16x8 af[2], bfr[4];
#pragma unroll
    for (int mt = 0; mt < 2; ++mt)
      af[mt] = *(const bf16x8*)(As[cur] + (w * 32 + mt * 16 + ln) * 32 + quad * 8);
#pragma unroll
    for (int nt = 0; nt < 4; ++nt)
      bfr[nt] = *(const bf16x8*)(Bs[cur] + (nt * 16 + ln) * 32 + quad * 8);
#pragma unroll
    for (int mt = 0; mt < 2; ++mt)
#pragma unroll
      for (int nt = 0; nt < 4; ++nt)
        acc[mt][nt] = __builtin_amdgcn_mfma_f32_16x16x32_bf16(af[mt], bfr[nt], acc[mt][nt], 0, 0, 0);
    cur ^= 1;
  }
  const int row0 = mb * 128 + w * 32, col0 = nb * 64;
#pragma unroll
  for (int mt = 0; mt < 2; ++mt)
#pragma unroll
    for (int nt = 0; nt < 4; ++nt)
#pragma unroll
      for (int r = 0; r < 4; ++r) {
        int row = row0 + mt * 16 + quad * 4 + r;
        int col = col0 + nt * 16 + ln;
        C[(size_t)row * N + col] = acc[mt][nt][r];
      }
}

// ---------------- flash attention: 128q block, 4 waves x 32q, 64-kv tiles -----
// R6 (T12): swapped QK^T + in-register P transpose (cvt_pk + permlane swaps);
// P never touches LDS. Bank conflicts measured 0 after R5 swizzle.
// R7 (T3-min): K/V LDS double-buffer, one barrier per iter.
// R10: softmax poly 3 packed ops. 69.9 µs measured — unchanged this round.
__global__ __launch_bounds__(256, 4) void attn(
    const unsigned short* __restrict__ Qn, const unsigned short* __restrict__ Kn,
    const unsigned short* __restrict__ Vtg, unsigned short* __restrict__ O) {
  __shared__ __align__(16) unsigned short Ks[2][4096];   // 64kv x 64d fragment chunks
  __shared__ __align__(16) unsigned short Vs[2][4096];   // 64d x 64kv (V^T) chunks
  const int t = threadIdx.x, w = t >> 6, l = t & 63;
  const int quad = l >> 4, ln = l & 15;
  const int bid = blockIdx.x;
  const int qt = 15 - (bid >> 6);
  const int bh = bid & 63;
  const int h = bh & 15, b = bh >> 4;
  const int q0 = qt * 128;
  const int wq0 = q0 + w * 32;
  const unsigned short* Qh = Qn + ((size_t)(b * 16 + h)) * SEQ * 64;
  const unsigned short* Kg = Kn + ((size_t)(b * 4 + (h >> 2))) * SEQ * 64;
  const unsigned short* Vg = Vtg + ((size_t)(b * 4 + (h >> 2))) * 64 * SEQ;
  const int lrow = l >> 2;
  // pre-swizzled global 16B-slot within each 64B chunk-row (involution with read)
  const int lswz = (((l & 3) ^ ((lrow >> 1) & 3)) * 8);
  // swizzled read slot: LDS slot j holds global col j ^ ((row>>1)&3); row = ln
  const int qsw = (quad ^ ((ln >> 1) & 3)) << 4;

  bf16x8 aq[2][2];
#pragma unroll
  for (int mt = 0; mt < 2; ++mt)
#pragma unroll
    for (int ks = 0; ks < 2; ++ks)
      aq[mt][ks] = *(const bf16x8*)(Qh + (size_t)(wq0 + mt * 16 + ln) * 64 + ks * 32 + quad * 8);
  f32x4 o_acc[2][4] = {};
  f32x2 lp[2] = {};

  const float Cc  = 0.18033688011112042f;  // ASCALE * log2(e)
  const float B1c = -1.0436160e-6f;        // Cc * (-(ASCALE/CAP)^2 / 3)
  const float M2  = 11.541560327f;         // 8 * log2(e)
  const int qr0 = wq0 + ln;                // this lane's q row (within-mt base)

  const int jmax = 2 * qt + 2;

  // prologue: stage kv-tile 0 into buffer 0
#pragma unroll
  for (int i = 0; i < 2; ++i) {
    int s = w * 2 + i;
    int snt = s >> 1, sks = s & 1;
    async_copy16((char*)Ks[0] + s * 1024,
                 Kg + (size_t)(snt * 16 + lrow) * 64 + sks * 32 + lswz);
    async_copy16((char*)Vs[0] + s * 1024,
                 Vg + (size_t)(snt * 16 + lrow) * SEQ + sks * 32 + lswz);
  }

  for (int jj = 0; jj < jmax; ++jj) {
    const int kv0 = jj * 64;
    const int cur = jj & 1;
    // barrier: (a) drains this wave's outstanding global_load_lds (vmcnt) so
    // buf[cur] staged by prior iter is visible; (b) all waves' ds_reads of
    // buf[cur^1] from prior iter are done (lgkm drained) so restaging is safe.
    __syncthreads();
    if (jj + 1 < jmax) {
      const int kvn = kv0 + 64;
#pragma unroll
      for (int i = 0; i < 2; ++i) {
        int s = w * 2 + i;
        int snt = s >> 1, sks = s & 1;
        async_copy16((char*)Ks[cur ^ 1] + s * 1024,
                     Kg + (size_t)(kvn + snt * 16 + lrow) * 64 + sks * 32 + lswz);
        async_copy16((char*)Vs[cur ^ 1] + s * 1024,
                     Vg + (size_t)(snt * 16 + lrow) * SEQ + kvn + sks * 32 + lswz);
      }
    }
    if (kv0 > wq0 + 31) continue;   // wave fully above diagonal (no barrier below)

    // S^T = K Q^T (swapped operands): st[nt][mt] lane holds
    // P[q = mt*16+ln][kv = nt*16 + quad*4 + r]
    f32x4 st[4][2] = {};
    __builtin_amdgcn_s_setprio(1);
#pragma unroll
    for (int nt = 0; nt < 4; ++nt)
#pragma unroll
      for (int ks = 0; ks < 2; ++ks) {
        bf16x8 bk = *(const bf16x8*)((char*)Ks[cur] + (nt * 2 + ks) * 1024 + ln * 64 + qsw);
        st[nt][0] = __builtin_amdgcn_mfma_f32_16x16x32_bf16(bk, aq[0][ks], st[nt][0], 0, 0, 0);
        st[nt][1] = __builtin_amdgcn_mfma_f32_16x16x32_bf16(bk, aq[1][ks], st[nt][1], 0, 0, 0);
      }
    __builtin_amdgcn_s_setprio(0);

    const bool needMask = (kv0 + 63 > wq0);
    bf16x8 ap[2][2];
#pragma unroll
    for (int mt = 0; mt < 2; ++mt) {
      const int qrow = qr0 + mt * 16;
      unsigned Wp[4][2];
#pragma unroll
      for (int nt = 0; nt < 4; ++nt)
#pragma unroll
        for (int rp = 0; rp < 2; ++rp) {
          f32x2 s = { st[nt][mt][rp * 2], st[nt][mt][rp * 2 + 1] };
          f32x2 s2 = s * s;                       // v_pk_mul_f32
          f32x2 tt = s2 * B1c + Cc;               // v_pk_fma_f32
          f32x2 arg = s * tt - M2;                // v_pk_fma_f32
          float pr0 = fexp2(arg.x), pr1 = fexp2(arg.y);
          if (needMask) {
            const int kvb = kv0 + nt * 16 + quad * 4 + rp * 2;
            if (kvb > qrow)     pr0 = 0.0f;
            if (kvb + 1 > qrow) pr1 = 0.0f;
          }
          lp[mt] += (f32x2){pr0, pr1};            // v_pk_add_f32
          unsigned wpk;
          asm("v_cvt_pk_bf16_f32 %0, %1, %2" : "=v"(wpk) : "v"(pr0), "v"(pr1));
          Wp[nt][rp] = wpk;
        }
      // in-register transpose of kv ownership: [3:2]=quad -> [4:3]=quad
#pragma unroll
      for (int ks = 0; ks < 2; ++ks) {
        unsigned a0 = Wp[2 * ks][0], b0 = Wp[2 * ks + 1][0];
        unsigned a1 = Wp[2 * ks][1], b1 = Wp[2 * ks + 1][1];
        asm("v_permlane32_swap_b32 %0, %1" : "+v"(a0), "+v"(b0));
        asm("v_permlane16_swap_b32 %0, %1" : "+v"(a0), "+v"(b0));
        asm("v_permlane32_swap_b32 %0, %1" : "+v"(a1), "+v"(b1));
        asm("v_permlane16_swap_b32 %0, %1" : "+v"(a1), "+v"(b1));
        union { u32x4 u; bf16x8 bv; } cc;
        cc.u = (u32x4){a0, a1, b0, b1};
        ap[mt][ks] = cc.bv;
      }
    }

    // O += P V : each bv feeds both m-tiles
    __builtin_amdgcn_s_setprio(1);
#pragma unroll
    for (int nt = 0; nt < 4; ++nt)
#pragma unroll
      for (int ks = 0; ks < 2; ++ks) {
        bf16x8 bv = *(const bf16x8*)((char*)Vs[cur] + (nt * 2 + ks) * 1024 + ln * 64 + qsw);
        o_acc[0][nt] = __builtin_amdgcn_mfma_f32_16x16x32_bf16(ap[0][ks], bv, o_acc[0][nt], 0, 0, 0);
        o_acc[1][nt] = __builtin_amdgcn_mfma_f32_16x16x32_bf16(ap[1][ks], bv, o_acc[1][nt], 0, 0, 0);
      }
    __builtin_amdgcn_s_setprio(0);
  }

  // epilogue: row sums live per-lane at q=ln; reduce over quads, then
  // redistribute to the o_acc row owner (q = quad*4+r)
  float invl[2][4];
#pragma unroll
  for (int mt = 0; mt < 2; ++mt) {
    float s = lp[mt].x + lp[mt].y;
    s += __shfl_xor(s, 16, 64);
    s += __shfl_xor(s, 32, 64);
#pragma unroll
    for (int r = 0; r < 4; ++r)
      invl[mt][r] = __builtin_amdgcn_rcpf(__shfl(s, quad * 4 + r, 64));
  }
#pragma unroll
  for (int mt = 0; mt < 2; ++mt)
#pragma unroll
    for (int nt = 0; nt < 4; ++nt)
#pragma unroll
      for (int r = 0; r < 4; ++r) {
        int qrow = wq0 + mt * 16 + quad * 4 + r;
        int col = h * 64 + nt * 16 + ln;
        O[((size_t)(b * SEQ + qrow)) * 1024 + col] = f2bf_hup(o_acc[mt][nt][r] * invl[mt][r]);
      }
}

// ---------------- launch ----------------
extern "C" void kernel_launch(void* const* d_in, const int* in_sizes, int n_in,
                              void* d_out, int out_size, void* d_ws, size_t ws_size,
                              hipStream_t stream) {
  const float* x  = (const float*)d_in[0];
  const float* Wq = (const float*)d_in[1];
  const float* Wk = (const float*)d_in[2];
  const float* Wv = (const float*)d_in[3];
  const float* Wo = (const float*)d_in[4];
  const float* qw = (const float*)d_in[5];
  const float* kw = (const float*)d_in[6];
  float* out = (float*)d_out;

  char* ws = (char*)d_ws;
  unsigned short* xb   = (unsigned short*)(ws);                 // 16,777,216
  unsigned short* wqkv = (unsigned short*)(ws + 16777216);      //  3,145,728
  unsigned short* wo   = (unsigned short*)(ws + 19922944);      //  2,097,152
  unsigned short* Qn   = (unsigned short*)(ws + 22020096);      // 16,777,216
  unsigned short* Kn   = (unsigned short*)(ws + 38797312);      //  4,194,304
  unsigned short* Vtg  = (unsigned short*)(ws + 42991616);      //  4,194,304
  unsigned short* Ob   = (unsigned short*)(ws + 47185920);      // 16,777,216  -> ~64 MB

  cvt_all<<<10752, 256, 0, stream>>>(x, Wq, Wk, Wv, Wo, xb, wqkv, wo);
  gemm_qkv<<<dim3(MTOK / 128, NQKV / 64), 256, 0, stream>>>(xb, wqkv, qw, kw, Qn, Kn, Vtg);
  attn<<<1024, 256, 0, stream>>>(Qn, Kn, Vtg, Ob);
  gemm_bt_f32<<<dim3(MTOK / 128, 1024 / 64), 256, 0, stream>>>(Ob, wo, out, MTOK, 1024, 1024);
}

// Round 10
// 211.529 us; speedup vs baseline: 1.0544x; 1.0544x over previous
//
#include <hip/hip_runtime.h>
#include <hip/hip_bf16.h>
#include <math.h>
#include <stdint.h>

#define D_MODEL 1024
#define NHEADS  16
#define NKV     4
#define HD      64
#define SEQ     2048
#define BATCH   4
#define MTOK    (BATCH*SEQ)            // 8192 tokens
#define NQKV    (D_MODEL + 2*NKV*HD)   // 1536
#define ASCALE  0.125f
#define CAP     30.0f

using f32x4  = __attribute__((ext_vector_type(4))) float;
using f32x2  = __attribute__((ext_vector_type(2))) float;
using bf16x8 = __attribute__((ext_vector_type(8))) short;
using u32x4  = __attribute__((ext_vector_type(4))) unsigned int;

__device__ __forceinline__ unsigned short f2bf(float f) {
  union { float f; unsigned u; } v; v.f = f;
  unsigned u = v.u + 0x7fffu + ((v.u >> 16) & 1u);
  return (unsigned short)(u >> 16);
}
__device__ __forceinline__ unsigned short f2bf_hup(float f) {  // round-half-up
  union { float f; unsigned u; } v; v.f = f;
  return (unsigned short)((v.u + 0x8000u) >> 16);
}
__device__ __forceinline__ float fexp2(float x) {   // raw v_exp_f32
  return __builtin_amdgcn_exp2f(x);
}
__device__ __forceinline__ void async_copy16(void* lds, const void* g) {
  __builtin_amdgcn_global_load_lds(
      (const __attribute__((address_space(1))) unsigned int*)(uintptr_t)g,
      (__attribute__((address_space(3))) unsigned int*)(uintptr_t)lds, 16, 0, 0);
}

// ---------------- fused fp32 -> bf16 convert for all 5 inputs ----------------
__global__ __launch_bounds__(256) void cvt_all(
    const float* __restrict__ x, const float* __restrict__ wq,
    const float* __restrict__ wk, const float* __restrict__ wv,
    const float* __restrict__ wo,
    unsigned short* __restrict__ xb, unsigned short* __restrict__ wqkv,
    unsigned short* __restrict__ wob) {
  const long i = (long)(blockIdx.x * 256 + threadIdx.x) * 4;
  const float* src; unsigned short* dst; long off;
  if (i < 8388608L)      { src = x;  dst = xb;             off = i; }
  else if (i < 9437184L) { src = wq; dst = wqkv;           off = i - 8388608L; }
  else if (i < 9699328L) { src = wk; dst = wqkv + 1048576; off = i - 9437184L; }
  else if (i < 9961472L) { src = wv; dst = wqkv + 1310720; off = i - 9699328L; }
  else                   { src = wo; dst = wob;            off = i - 9961472L; }
  float4 v = *(const float4*)(src + off);
  ushort4 o; o.x = f2bf(v.x); o.y = f2bf(v.y); o.z = f2bf(v.z); o.w = f2bf(v.w);
  *(ushort4*)(dst + off) = o;
}

// ---------------- QKV GEMM with fused RMSNorm + RoPE + layout epilogue --------
// R14: byte-identical revert to the R8/214.8µs-measured config (128² tile,
// 4 waves, sync-dbuf {sync; prefetch->buf^1; compute}). All five deviations
// tried since measured <= 0: 256² 2ph (-14, grid underfill), XCD remap (-4,
// L3-resident inputs), counted-vmcnt (0, co-residency already hides drain),
// fused x-cvt (-8, doubled LDS bytes), 128x64 tile (-8, LDS-traffic/FLOP up).
// This configuration is the measured local optimum for K=1024 skinny shapes.
__global__ __launch_bounds__(256) void gemm_qkv(
    const unsigned short* __restrict__ A, const unsigned short* __restrict__ B,
    const float* __restrict__ qw, const float* __restrict__ kw,
    unsigned short* __restrict__ Qn, unsigned short* __restrict__ Kn,
    unsigned short* __restrict__ Vt) {
  __shared__ __align__(16) unsigned short As[2][128 * 32];
  __shared__ __align__(16) unsigned short Bs[2][128 * 32];
  const int t = threadIdx.x;
  const int w = t >> 6, l = t & 63;
  const int mb = blockIdx.x, nb = blockIdx.y;
  const int wm = w & 1, wn = w >> 1;
  const int quad = l >> 4, ln = l & 15;
  const int K = D_MODEL;
  f32x4 acc[4][4] = {};
  const unsigned short* Ag = A + (size_t)(mb * 128 + w * 32) * K;
  const unsigned short* Bg = B + (size_t)(nb * 128 + w * 32) * K;
  const int lrow = l >> 2, lcol = (l & 3) * 8;
  const int wo16 = w * 2048 + l * 16;            // byte offset of this lane's slot

  // prologue: stage kb=0 into buffer 0
  async_copy16((char*)As[0] + wo16,        Ag + (size_t)lrow * K + lcol);
  async_copy16((char*)As[0] + wo16 + 1024, Ag + (size_t)(16 + lrow) * K + lcol);
  async_copy16((char*)Bs[0] + wo16,        Bg + (size_t)lrow * K + lcol);
  async_copy16((char*)Bs[0] + wo16 + 1024, Bg + (size_t)(16 + lrow) * K + lcol);

  int cur = 0;
  for (int kb = 0; kb < K; kb += 32) {
    __syncthreads();   // drains vmcnt: buf[cur] staged; prior reads of buf[cur^1] done
    if (kb + 32 < K) {
      const int kn = kb + 32;
      async_copy16((char*)As[cur ^ 1] + wo16,        Ag + (size_t)lrow * K + kn + lcol);
      async_copy16((char*)As[cur ^ 1] + wo16 + 1024, Ag + (size_t)(16 + lrow) * K + kn + lcol);
      async_copy16((char*)Bs[cur ^ 1] + wo16,        Bg + (size_t)lrow * K + kn + lcol);
      async_copy16((char*)Bs[cur ^ 1] + wo16 + 1024, Bg + (size_t)(16 + lrow) * K + kn + lcol);
    }
    bf16x8 af[4], bfr[4];
#pragma unroll
    for (int mt = 0; mt < 4; ++mt)
      af[mt] = *(const bf16x8*)(As[cur] + (wm * 64 + mt * 16 + ln) * 32 + quad * 8);
#pragma unroll
    for (int nt = 0; nt < 4; ++nt)
      bfr[nt] = *(const bf16x8*)(Bs[cur] + (wn * 64 + nt * 16 + ln) * 32 + quad * 8);
#pragma unroll
    for (int mt = 0; mt < 4; ++mt)
#pragma unroll
      for (int nt = 0; nt < 4; ++nt)
        acc[mt][nt] = __builtin_amdgcn_mfma_f32_16x16x32_bf16(af[mt], bfr[nt], acc[mt][nt], 0, 0, 0);
    cur ^= 1;
  }

  const int hs = nb * 2 + wn;                    // head slot 0..23
  const int bB = mb >> 4;
  const int sBase = ((mb & 15) * 128) + wm * 64;

  if (hs < 20) {
    const float* wgt = (hs < 16) ? qw : kw;
    float wv_[4];
#pragma unroll
    for (int nt = 0; nt < 4; ++nt) wv_[nt] = wgt[nt * 16 + ln];
    const float f0 = __expf(-(float)ln * 0.2878231366f);   // ln(10000)/32
    const float f1 = f0 * 0.01f;
    unsigned short* dst = (hs < 16)
        ? Qn + (size_t)(bB * 16 + hs) * SEQ * 64
        : Kn + (size_t)(bB * 4 + (hs - 16)) * SEQ * 64;
#pragma unroll
    for (int mt = 0; mt < 4; ++mt) {
#pragma unroll
      for (int r = 0; r < 4; ++r) {
        const int sTok = sBase + mt * 16 + quad * 4 + r;
        float ss = 0.f;
#pragma unroll
        for (int nt = 0; nt < 4; ++nt) ss = fmaf(acc[mt][nt][r], acc[mt][nt][r], ss);
        ss += __shfl_xor(ss, 1, 64); ss += __shfl_xor(ss, 2, 64);
        ss += __shfl_xor(ss, 4, 64); ss += __shfl_xor(ss, 8, 64);
        const float inv = rsqrtf(ss * (1.0f / 64.0f) + 1e-6f);
        float xn[4];
#pragma unroll
        for (int nt = 0; nt < 4; ++nt) xn[nt] = acc[mt][nt][r] * inv * wv_[nt];
        float sn0, cs0, sn1, cs1;
        __sincosf((float)sTok * f0, &sn0, &cs0);
        __sincosf((float)sTok * f1, &sn1, &cs1);
        const float o0 = xn[0] * cs0 - xn[2] * sn0;
        const float o1 = xn[1] * cs1 - xn[3] * sn1;
        const float o2 = xn[2] * cs0 + xn[0] * sn0;
        const float o3 = xn[3] * cs1 + xn[1] * sn1;
        const size_t ro = (size_t)sTok * 64 + ln;
        dst[ro]      = f2bf(o0);
        dst[ro + 16] = f2bf(o1);
        dst[ro + 32] = f2bf(o2);
        dst[ro + 48] = f2bf(o3);
      }
    }
  } else {
    unsigned short* dst = Vt + (size_t)(bB * 4 + (hs - 20)) * 64 * SEQ;
#pragma unroll
    for (int mt = 0; mt < 4; ++mt)
#pragma unroll
      for (int nt = 0; nt < 4; ++nt)
#pragma unroll
        for (int r = 0; r < 4; ++r) {
          const int sTok = sBase + mt * 16 + quad * 4 + r;
          dst[(size_t)(nt * 16 + ln) * SEQ + sTok] = f2bf(acc[mt][nt][r]);
        }
  }
}

// ---------------- GEMM: C[M,N] f32 = A[M,K]bf16 * B[N,K]bf16^T ----------------
// R14: byte-identical revert to the R8/214.8µs-measured config.
__global__ __launch_bounds__(256) void gemm_bt_f32(
    const unsigned short* __restrict__ A, const unsigned short* __restrict__ B,
    float* __restrict__ C, int M, int N, int K) {
  __shared__ __align__(16) unsigned short As[2][128 * 32];
  __shared__ __align__(16) unsigned short Bs[2][128 * 32];
  const int t = threadIdx.x;
  const int w = t >> 6, l = t & 63;
  const int mb = blockIdx.x, nb = blockIdx.y;
  const int wm = w & 1, wn = w >> 1;
  f32x4 acc[4][4] = {};
  const unsigned short* Ag = A + (size_t)(mb * 128 + w * 32) * K;
  const unsigned short* Bg = B + (size_t)(nb * 128 + w * 32) * K;
  const int lrow = l >> 2, lcol = (l & 3) * 8;
  const int wo16 = w * 2048 + l * 16;

  async_copy16((char*)As[0] + wo16,        Ag + (size_t)lrow * K + lcol);
  async_copy16((char*)As[0] + wo16 + 1024, Ag + (size_t)(16 + lrow) * K + lcol);
  async_copy16((char*)Bs[0] + wo16,        Bg + (size_t)lrow * K + lcol);
  async_copy16((char*)Bs[0] + wo16 + 1024, Bg + (size_t)(16 + lrow) * K + lcol);

  int cur = 0;
  for (int kb = 0; kb < K; kb += 32) {
    __syncthreads();
    if (kb + 32 < K) {
      const int kn = kb + 32;
      async_copy16((char*)As[cur ^ 1] + wo16,        Ag + (size_t)lrow * K + kn + lcol);
      async_copy16((char*)As[cur ^ 1] + wo16 + 1024, Ag + (size_t)(16 + lrow) * K + kn + lcol);
      async_copy16((char*)Bs[cur ^ 1] + wo16,        Bg + (size_t)lrow * K + kn + lcol);
      async_copy16((char*)Bs[cur ^ 1] + wo16 + 1024, Bg + (size_t)(16 + lrow) * K + kn + lcol);
    }
    bf16x8 af[4], bfr[4];
#pragma unroll
    for (int mt = 0; mt < 4; ++mt)
      af[mt] = *(const bf16x8*)(As[cur] + (wm * 64 + mt * 16 + (l & 15)) * 32 + (l >> 4) * 8);
#pragma unroll
    for (int nt = 0; nt < 4; ++nt)
      bfr[nt] = *(const bf16x8*)(Bs[cur] + (wn * 64 + nt * 16 + (l & 15)) * 32 + (l >> 4) * 8);
#pragma unroll
    for (int mt = 0; mt < 4; ++mt)
#pragma unroll
      for (int nt = 0; nt < 4; ++nt)
        acc[mt][nt] = __builtin_amdgcn_mfma_f32_16x16x32_bf16(af[mt], bfr[nt], acc[mt][nt], 0, 0, 0);
    cur ^= 1;
  }
  const int row0 = mb * 128 + wm * 64, col0 = nb * 128 + wn * 64;
#pragma unroll
  for (int mt = 0; mt < 4; ++mt)
#pragma unroll
    for (int nt = 0; nt < 4; ++nt)
#pragma unroll
      for (int r = 0; r < 4; ++r) {
        int row = row0 + mt * 16 + (l >> 4) * 4 + r;
        int col = col0 + nt * 16 + (l & 15);
        C[(size_t)row * N + col] = acc[mt][nt][r];
      }
}

// ---------------- flash attention: 128q block, 4 waves x 32q, 64-kv tiles -----
// R6 (T12): swapped QK^T + in-register P transpose (cvt_pk + permlane swaps);
// P never touches LDS. Bank conflicts measured 0 after R5 swizzle.
// R7 (T3-min): K/V LDS double-buffer, one barrier per iter.
// R10: softmax poly 3 packed ops. Measured 69.9-70.0 µs (stable across 4 runs).
__global__ __launch_bounds__(256, 4) void attn(
    const unsigned short* __restrict__ Qn, const unsigned short* __restrict__ Kn,
    const unsigned short* __restrict__ Vtg, unsigned short* __restrict__ O) {
  __shared__ __align__(16) unsigned short Ks[2][4096];   // 64kv x 64d fragment chunks
  __shared__ __align__(16) unsigned short Vs[2][4096];   // 64d x 64kv (V^T) chunks
  const int t = threadIdx.x, w = t >> 6, l = t & 63;
  const int quad = l >> 4, ln = l & 15;
  const int bid = blockIdx.x;
  const int qt = 15 - (bid >> 6);
  const int bh = bid & 63;
  const int h = bh & 15, b = bh >> 4;
  const int q0 = qt * 128;
  const int wq0 = q0 + w * 32;
  const unsigned short* Qh = Qn + ((size_t)(b * 16 + h)) * SEQ * 64;
  const unsigned short* Kg = Kn + ((size_t)(b * 4 + (h >> 2))) * SEQ * 64;
  const unsigned short* Vg = Vtg + ((size_t)(b * 4 + (h >> 2))) * 64 * SEQ;
  const int lrow = l >> 2;
  // pre-swizzled global 16B-slot within each 64B chunk-row (involution with read)
  const int lswz = (((l & 3) ^ ((lrow >> 1) & 3)) * 8);
  // swizzled read slot: LDS slot j holds global col j ^ ((row>>1)&3); row = ln
  const int qsw = (quad ^ ((ln >> 1) & 3)) << 4;

  bf16x8 aq[2][2];
#pragma unroll
  for (int mt = 0; mt < 2; ++mt)
#pragma unroll
    for (int ks = 0; ks < 2; ++ks)
      aq[mt][ks] = *(const bf16x8*)(Qh + (size_t)(wq0 + mt * 16 + ln) * 64 + ks * 32 + quad * 8);
  f32x4 o_acc[2][4] = {};
  f32x2 lp[2] = {};

  const float Cc  = 0.18033688011112042f;  // ASCALE * log2(e)
  const float B1c = -1.0436160e-6f;        // Cc * (-(ASCALE/CAP)^2 / 3)
  const float M2  = 11.541560327f;         // 8 * log2(e)
  const int qr0 = wq0 + ln;                // this lane's q row (within-mt base)

  const int jmax = 2 * qt + 2;

  // prologue: stage kv-tile 0 into buffer 0
#pragma unroll
  for (int i = 0; i < 2; ++i) {
    int s = w * 2 + i;
    int snt = s >> 1, sks = s & 1;
    async_copy16((char*)Ks[0] + s * 1024,
                 Kg + (size_t)(snt * 16 + lrow) * 64 + sks * 32 + lswz);
    async_copy16((char*)Vs[0] + s * 1024,
                 Vg + (size_t)(snt * 16 + lrow) * SEQ + sks * 32 + lswz);
  }

  for (int jj = 0; jj < jmax; ++jj) {
    const int kv0 = jj * 64;
    const int cur = jj & 1;
    // barrier: (a) drains this wave's outstanding global_load_lds (vmcnt) so
    // buf[cur] staged by prior iter is visible; (b) all waves' ds_reads of
    // buf[cur^1] from prior iter are done (lgkm drained) so restaging is safe.
    __syncthreads();
    if (jj + 1 < jmax) {
      const int kvn = kv0 + 64;
#pragma unroll
      for (int i = 0; i < 2; ++i) {
        int s = w * 2 + i;
        int snt = s >> 1, sks = s & 1;
        async_copy16((char*)Ks[cur ^ 1] + s * 1024,
                     Kg + (size_t)(kvn + snt * 16 + lrow) * 64 + sks * 32 + lswz);
        async_copy16((char*)Vs[cur ^ 1] + s * 1024,
                     Vg + (size_t)(snt * 16 + lrow) * SEQ + kvn + sks * 32 + lswz);
      }
    }
    if (kv0 > wq0 + 31) continue;   // wave fully above diagonal (no barrier below)

    // S^T = K Q^T (swapped operands): st[nt][mt] lane holds
    // P[q = mt*16+ln][kv = nt*16 + quad*4 + r]
    f32x4 st[4][2] = {};
    __builtin_amdgcn_s_setprio(1);
#pragma unroll
    for (int nt = 0; nt < 4; ++nt)
#pragma unroll
      for (int ks = 0; ks < 2; ++ks) {
        bf16x8 bk = *(const bf16x8*)((char*)Ks[cur] + (nt * 2 + ks) * 1024 + ln * 64 + qsw);
        st[nt][0] = __builtin_amdgcn_mfma_f32_16x16x32_bf16(bk, aq[0][ks], st[nt][0], 0, 0, 0);
        st[nt][1] = __builtin_amdgcn_mfma_f32_16x16x32_bf16(bk, aq[1][ks], st[nt][1], 0, 0, 0);
      }
    __builtin_amdgcn_s_setprio(0);

    const bool needMask = (kv0 + 63 > wq0);
    bf16x8 ap[2][2];
#pragma unroll
    for (int mt = 0; mt < 2; ++mt) {
      const int qrow = qr0 + mt * 16;
      unsigned Wp[4][2];
#pragma unroll
      for (int nt = 0; nt < 4; ++nt)
#pragma unroll
        for (int rp = 0; rp < 2; ++rp) {
          f32x2 s = { st[nt][mt][rp * 2], st[nt][mt][rp * 2 + 1] };
          f32x2 s2 = s * s;                       // v_pk_mul_f32
          f32x2 tt = s2 * B1c + Cc;               // v_pk_fma_f32
          f32x2 arg = s * tt - M2;                // v_pk_fma_f32
          float pr0 = fexp2(arg.x), pr1 = fexp2(arg.y);
          if (needMask) {
            const int kvb = kv0 + nt * 16 + quad * 4 + rp * 2;
            if (kvb > qrow)     pr0 = 0.0f;
            if (kvb + 1 > qrow) pr1 = 0.0f;
          }
          lp[mt] += (f32x2){pr0, pr1};            // v_pk_add_f32
          unsigned wpk;
          asm("v_cvt_pk_bf16_f32 %0, %1, %2" : "=v"(wpk) : "v"(pr0), "v"(pr1));
          Wp[nt][rp] = wpk;
        }
      // in-register transpose of kv ownership: [3:2]=quad -> [4:3]=quad
#pragma unroll
      for (int ks = 0; ks < 2; ++ks) {
        unsigned a0 = Wp[2 * ks][0], b0 = Wp[2 * ks + 1][0];
        unsigned a1 = Wp[2 * ks][1], b1 = Wp[2 * ks + 1][1];
        asm("v_permlane32_swap_b32 %0, %1" : "+v"(a0), "+v"(b0));
        asm("v_permlane16_swap_b32 %0, %1" : "+v"(a0), "+v"(b0));
        asm("v_permlane32_swap_b32 %0, %1" : "+v"(a1), "+v"(b1));
        asm("v_permlane16_swap_b32 %0, %1" : "+v"(a1), "+v"(b1));
        union { u32x4 u; bf16x8 bv; } cc;
        cc.u = (u32x4){a0, a1, b0, b1};
        ap[mt][ks] = cc.bv;
      }
    }

    // O += P V : each bv feeds both m-tiles
    __builtin_amdgcn_s_setprio(1);
#pragma unroll
    for (int nt = 0; nt < 4; ++nt)
#pragma unroll
      for (int ks = 0; ks < 2; ++ks) {
        bf16x8 bv = *(const bf16x8*)((char*)Vs[cur] + (nt * 2 + ks) * 1024 + ln * 64 + qsw);
        o_acc[0][nt] = __builtin_amdgcn_mfma_f32_16x16x32_bf16(ap[0][ks], bv, o_acc[0][nt], 0, 0, 0);
        o_acc[1][nt] = __builtin_amdgcn_mfma_f32_16x16x32_bf16(ap[1][ks], bv, o_acc[1][nt], 0, 0, 0);
      }
    __builtin_amdgcn_s_setprio(0);
  }

  // epilogue: row sums live per-lane at q=ln; reduce over quads, then
  // redistribute to the o_acc row owner (q = quad*4+r)
  float invl[2][4];
#pragma unroll
  for (int mt = 0; mt < 2; ++mt) {
    float s = lp[mt].x + lp[mt].y;
    s += __shfl_xor(s, 16, 64);
    s += __shfl_xor(s, 32, 64);
#pragma unroll
    for (int r = 0; r < 4; ++r)
      invl[mt][r] = __builtin_amdgcn_rcpf(__shfl(s, quad * 4 + r, 64));
  }
#pragma unroll
  for (int mt = 0; mt < 2; ++mt)
#pragma unroll
    for (int nt = 0; nt < 4; ++nt)
#pragma unroll
      for (int r = 0; r < 4; ++r) {
        int qrow = wq0 + mt * 16 + quad * 4 + r;
        int col = h * 64 + nt * 16 + ln;
        O[((size_t)(b * SEQ + qrow)) * 1024 + col] = f2bf_hup(o_acc[mt][nt][r] * invl[mt][r]);
      }
}

// ---------------- launch ----------------
extern "C" void kernel_launch(void* const* d_in, const int* in_sizes, int n_in,
                              void* d_out, int out_size, void* d_ws, size_t ws_size,
                              hipStream_t stream) {
  const float* x  = (const float*)d_in[0];
  const float* Wq = (const float*)d_in[1];
  const float* Wk = (const float*)d_in[2];
  const float* Wv = (const float*)d_in[3];
  const float* Wo = (const float*)d_in[4];
  const float* qw = (const float*)d_in[5];
  const float* kw = (const float*)d_in[6];
  float* out = (float*)d_out;

  char* ws = (char*)d_ws;
  unsigned short* xb   = (unsigned short*)(ws);                 // 16,777,216
  unsigned short* wqkv = (unsigned short*)(ws + 16777216);      //  3,145,728
  unsigned short* wo   = (unsigned short*)(ws + 19922944);      //  2,097,152
  unsigned short* Qn   = (unsigned short*)(ws + 22020096);      // 16,777,216
  unsigned short* Kn   = (unsigned short*)(ws + 38797312);      //  4,194,304
  unsigned short* Vtg  = (unsigned short*)(ws + 42991616);      //  4,194,304
  unsigned short* Ob   = (unsigned short*)(ws + 47185920);      // 16,777,216  -> ~64 MB

  cvt_all<<<10752, 256, 0, stream>>>(x, Wq, Wk, Wv, Wo, xb, wqkv, wo);
  gemm_qkv<<<dim3(MTOK / 128, NQKV / 128), 256, 0, stream>>>(xb, wqkv, qw, kw, Qn, Kn, Vtg);
  attn<<<1024, 256, 0, stream>>>(Qn, Kn, Vtg, Ob);
  gemm_bt_f32<<<dim3(MTOK / 128, 1024 / 128), 256, 0, stream>>>(Ob, wo, out, MTOK, 1024, 1024);
}

// Round 11
// 211.211 us; speedup vs baseline: 1.0560x; 1.0015x over previous
//
#include <hip/hip_runtime.h>
#include <hip/hip_bf16.h>
#include <math.h>
#include <stdint.h>

#define D_MODEL 1024
#define NHEADS  16
#define NKV     4
#define HD      64
#define SEQ     2048
#define BATCH   4
#define MTOK    (BATCH*SEQ)            // 8192 tokens
#define NQKV    (D_MODEL + 2*NKV*HD)   // 1536
#define ASCALE  0.125f
#define CAP     30.0f

using f32x4  = __attribute__((ext_vector_type(4))) float;
using f32x2  = __attribute__((ext_vector_type(2))) float;
using bf16x8 = __attribute__((ext_vector_type(8))) short;
using u32x4  = __attribute__((ext_vector_type(4))) unsigned int;

__device__ __forceinline__ unsigned short f2bf(float f) {
  union { float f; unsigned u; } v; v.f = f;
  unsigned u = v.u + 0x7fffu + ((v.u >> 16) & 1u);
  return (unsigned short)(u >> 16);
}
__device__ __forceinline__ unsigned short f2bf_hup(float f) {  // round-half-up
  union { float f; unsigned u; } v; v.f = f;
  return (unsigned short)((v.u + 0x8000u) >> 16);
}
__device__ __forceinline__ float fexp2(float x) {   // raw v_exp_f32
  return __builtin_amdgcn_exp2f(x);
}
__device__ __forceinline__ void async_copy16(void* lds, const void* g) {
  __builtin_amdgcn_global_load_lds(
      (const __attribute__((address_space(1))) unsigned int*)(uintptr_t)g,
      (__attribute__((address_space(3))) unsigned int*)(uintptr_t)lds, 16, 0, 0);
}

// ---------------- fused fp32 -> bf16 convert for all 5 inputs ----------------
__global__ __launch_bounds__(256) void cvt_all(
    const float* __restrict__ x, const float* __restrict__ wq,
    const float* __restrict__ wk, const float* __restrict__ wv,
    const float* __restrict__ wo,
    unsigned short* __restrict__ xb, unsigned short* __restrict__ wqkv,
    unsigned short* __restrict__ wob) {
  const long i = (long)(blockIdx.x * 256 + threadIdx.x) * 4;
  const float* src; unsigned short* dst; long off;
  if (i < 8388608L)      { src = x;  dst = xb;             off = i; }
  else if (i < 9437184L) { src = wq; dst = wqkv;           off = i - 8388608L; }
  else if (i < 9699328L) { src = wk; dst = wqkv + 1048576; off = i - 9437184L; }
  else if (i < 9961472L) { src = wv; dst = wqkv + 1310720; off = i - 9699328L; }
  else                   { src = wo; dst = wob;            off = i - 9961472L; }
  float4 v = *(const float4*)(src + off);
  ushort4 o; o.x = f2bf(v.x); o.y = f2bf(v.y); o.z = f2bf(v.z); o.w = f2bf(v.w);
  *(ushort4*)(dst + off) = o;
}

// ---------------- QKV GEMM with fused RMSNorm + RoPE + layout epilogue --------
// R14: the measured-best config (128² tile, 4 waves, sync-dbuf). All five
// structural deviations tried measured <= 0 (256² 2ph, XCD remap, counted
// vmcnt, fused x-cvt, 128x64 tile) — this is the local optimum for K=1024.
// R15: V-branch epilogue stores packed 4x2B -> 1x8B (r=0..3 are consecutive
// tokens along SEQ); addresses 8B-aligned (sBase/mt*16/quad*4 all mult of 4).
__global__ __launch_bounds__(256) void gemm_qkv(
    const unsigned short* __restrict__ A, const unsigned short* __restrict__ B,
    const float* __restrict__ qw, const float* __restrict__ kw,
    unsigned short* __restrict__ Qn, unsigned short* __restrict__ Kn,
    unsigned short* __restrict__ Vt) {
  __shared__ __align__(16) unsigned short As[2][128 * 32];
  __shared__ __align__(16) unsigned short Bs[2][128 * 32];
  const int t = threadIdx.x;
  const int w = t >> 6, l = t & 63;
  const int mb = blockIdx.x, nb = blockIdx.y;
  const int wm = w & 1, wn = w >> 1;
  const int quad = l >> 4, ln = l & 15;
  const int K = D_MODEL;
  f32x4 acc[4][4] = {};
  const unsigned short* Ag = A + (size_t)(mb * 128 + w * 32) * K;
  const unsigned short* Bg = B + (size_t)(nb * 128 + w * 32) * K;
  const int lrow = l >> 2, lcol = (l & 3) * 8;
  const int wo16 = w * 2048 + l * 16;            // byte offset of this lane's slot

  // prologue: stage kb=0 into buffer 0
  async_copy16((char*)As[0] + wo16,        Ag + (size_t)lrow * K + lcol);
  async_copy16((char*)As[0] + wo16 + 1024, Ag + (size_t)(16 + lrow) * K + lcol);
  async_copy16((char*)Bs[0] + wo16,        Bg + (size_t)lrow * K + lcol);
  async_copy16((char*)Bs[0] + wo16 + 1024, Bg + (size_t)(16 + lrow) * K + lcol);

  int cur = 0;
  for (int kb = 0; kb < K; kb += 32) {
    __syncthreads();   // drains vmcnt: buf[cur] staged; prior reads of buf[cur^1] done
    if (kb + 32 < K) {
      const int kn = kb + 32;
      async_copy16((char*)As[cur ^ 1] + wo16,        Ag + (size_t)lrow * K + kn + lcol);
      async_copy16((char*)As[cur ^ 1] + wo16 + 1024, Ag + (size_t)(16 + lrow) * K + kn + lcol);
      async_copy16((char*)Bs[cur ^ 1] + wo16,        Bg + (size_t)lrow * K + kn + lcol);
      async_copy16((char*)Bs[cur ^ 1] + wo16 + 1024, Bg + (size_t)(16 + lrow) * K + kn + lcol);
    }
    bf16x8 af[4], bfr[4];
#pragma unroll
    for (int mt = 0; mt < 4; ++mt)
      af[mt] = *(const bf16x8*)(As[cur] + (wm * 64 + mt * 16 + ln) * 32 + quad * 8);
#pragma unroll
    for (int nt = 0; nt < 4; ++nt)
      bfr[nt] = *(const bf16x8*)(Bs[cur] + (wn * 64 + nt * 16 + ln) * 32 + quad * 8);
#pragma unroll
    for (int mt = 0; mt < 4; ++mt)
#pragma unroll
      for (int nt = 0; nt < 4; ++nt)
        acc[mt][nt] = __builtin_amdgcn_mfma_f32_16x16x32_bf16(af[mt], bfr[nt], acc[mt][nt], 0, 0, 0);
    cur ^= 1;
  }

  const int hs = nb * 2 + wn;                    // head slot 0..23
  const int bB = mb >> 4;
  const int sBase = ((mb & 15) * 128) + wm * 64;

  if (hs < 20) {
    const float* wgt = (hs < 16) ? qw : kw;
    float wv_[4];
#pragma unroll
    for (int nt = 0; nt < 4; ++nt) wv_[nt] = wgt[nt * 16 + ln];
    const float f0 = __expf(-(float)ln * 0.2878231366f);   // ln(10000)/32
    const float f1 = f0 * 0.01f;
    unsigned short* dst = (hs < 16)
        ? Qn + (size_t)(bB * 16 + hs) * SEQ * 64
        : Kn + (size_t)(bB * 4 + (hs - 16)) * SEQ * 64;
#pragma unroll
    for (int mt = 0; mt < 4; ++mt) {
#pragma unroll
      for (int r = 0; r < 4; ++r) {
        const int sTok = sBase + mt * 16 + quad * 4 + r;
        float ss = 0.f;
#pragma unroll
        for (int nt = 0; nt < 4; ++nt) ss = fmaf(acc[mt][nt][r], acc[mt][nt][r], ss);
        ss += __shfl_xor(ss, 1, 64); ss += __shfl_xor(ss, 2, 64);
        ss += __shfl_xor(ss, 4, 64); ss += __shfl_xor(ss, 8, 64);
        const float inv = rsqrtf(ss * (1.0f / 64.0f) + 1e-6f);
        float xn[4];
#pragma unroll
        for (int nt = 0; nt < 4; ++nt) xn[nt] = acc[mt][nt][r] * inv * wv_[nt];
        float sn0, cs0, sn1, cs1;
        __sincosf((float)sTok * f0, &sn0, &cs0);
        __sincosf((float)sTok * f1, &sn1, &cs1);
        const float o0 = xn[0] * cs0 - xn[2] * sn0;
        const float o1 = xn[1] * cs1 - xn[3] * sn1;
        const float o2 = xn[2] * cs0 + xn[0] * sn0;
        const float o3 = xn[3] * cs1 + xn[1] * sn1;
        const size_t ro = (size_t)sTok * 64 + ln;
        dst[ro]      = f2bf(o0);
        dst[ro + 16] = f2bf(o1);
        dst[ro + 32] = f2bf(o2);
        dst[ro + 48] = f2bf(o3);
      }
    }
  } else {
    unsigned short* dst = Vt + (size_t)(bB * 4 + (hs - 20)) * 64 * SEQ;
#pragma unroll
    for (int mt = 0; mt < 4; ++mt)
#pragma unroll
      for (int nt = 0; nt < 4; ++nt) {
        const int sTok = sBase + mt * 16 + quad * 4;   // r=0..3 contiguous along SEQ
        ushort4 pv;
        pv.x = f2bf(acc[mt][nt][0]);
        pv.y = f2bf(acc[mt][nt][1]);
        pv.z = f2bf(acc[mt][nt][2]);
        pv.w = f2bf(acc[mt][nt][3]);
        *(ushort4*)(dst + (size_t)(nt * 16 + ln) * SEQ + sTok) = pv;
      }
  }
}

// ---------------- GEMM: C[M,N] f32 = A[M,K]bf16 * B[N,K]bf16^T ----------------
// R14: the measured-best config (sync-dbuf; counted-vmcnt reverted as neutral).
__global__ __launch_bounds__(256) void gemm_bt_f32(
    const unsigned short* __restrict__ A, const unsigned short* __restrict__ B,
    float* __restrict__ C, int M, int N, int K) {
  __shared__ __align__(16) unsigned short As[2][128 * 32];
  __shared__ __align__(16) unsigned short Bs[2][128 * 32];
  const int t = threadIdx.x;
  const int w = t >> 6, l = t & 63;
  const int mb = blockIdx.x, nb = blockIdx.y;
  const int wm = w & 1, wn = w >> 1;
  f32x4 acc[4][4] = {};
  const unsigned short* Ag = A + (size_t)(mb * 128 + w * 32) * K;
  const unsigned short* Bg = B + (size_t)(nb * 128 + w * 32) * K;
  const int lrow = l >> 2, lcol = (l & 3) * 8;
  const int wo16 = w * 2048 + l * 16;

  async_copy16((char*)As[0] + wo16,        Ag + (size_t)lrow * K + lcol);
  async_copy16((char*)As[0] + wo16 + 1024, Ag + (size_t)(16 + lrow) * K + lcol);
  async_copy16((char*)Bs[0] + wo16,        Bg + (size_t)lrow * K + lcol);
  async_copy16((char*)Bs[0] + wo16 + 1024, Bg + (size_t)(16 + lrow) * K + lcol);

  int cur = 0;
  for (int kb = 0; kb < K; kb += 32) {
    __syncthreads();
    if (kb + 32 < K) {
      const int kn = kb + 32;
      async_copy16((char*)As[cur ^ 1] + wo16,        Ag + (size_t)lrow * K + kn + lcol);
      async_copy16((char*)As[cur ^ 1] + wo16 + 1024, Ag + (size_t)(16 + lrow) * K + kn + lcol);
      async_copy16((char*)Bs[cur ^ 1] + wo16,        Bg + (size_t)lrow * K + kn + lcol);
      async_copy16((char*)Bs[cur ^ 1] + wo16 + 1024, Bg + (size_t)(16 + lrow) * K + kn + lcol);
    }
    bf16x8 af[4], bfr[4];
#pragma unroll
    for (int mt = 0; mt < 4; ++mt)
      af[mt] = *(const bf16x8*)(As[cur] + (wm * 64 + mt * 16 + (l & 15)) * 32 + (l >> 4) * 8);
#pragma unroll
    for (int nt = 0; nt < 4; ++nt)
      bfr[nt] = *(const bf16x8*)(Bs[cur] + (wn * 64 + nt * 16 + (l & 15)) * 32 + (l >> 4) * 8);
#pragma unroll
    for (int mt = 0; mt < 4; ++mt)
#pragma unroll
      for (int nt = 0; nt < 4; ++nt)
        acc[mt][nt] = __builtin_amdgcn_mfma_f32_16x16x32_bf16(af[mt], bfr[nt], acc[mt][nt], 0, 0, 0);
    cur ^= 1;
  }
  const int row0 = mb * 128 + wm * 64, col0 = nb * 128 + wn * 64;
#pragma unroll
  for (int mt = 0; mt < 4; ++mt)
#pragma unroll
    for (int nt = 0; nt < 4; ++nt)
#pragma unroll
      for (int r = 0; r < 4; ++r) {
        int row = row0 + mt * 16 + (l >> 4) * 4 + r;
        int col = col0 + nt * 16 + (l & 15);
        C[(size_t)row * N + col] = acc[mt][nt][r];
      }
}

// ---------------- flash attention: 128q block, 4 waves x 32q, 64-kv tiles -----
// R6 (T12): swapped QK^T + in-register P transpose (cvt_pk + permlane swaps);
// P never touches LDS. Bank conflicts measured 0 after R5 swizzle.
// R7 (T3-min): K/V LDS double-buffer, one barrier per iter.
// R10: softmax poly 3 packed ops. Measured 69.5-72.8 µs across runs (±2 noise).
__global__ __launch_bounds__(256, 4) void attn(
    const unsigned short* __restrict__ Qn, const unsigned short* __restrict__ Kn,
    const unsigned short* __restrict__ Vtg, unsigned short* __restrict__ O) {
  __shared__ __align__(16) unsigned short Ks[2][4096];   // 64kv x 64d fragment chunks
  __shared__ __align__(16) unsigned short Vs[2][4096];   // 64d x 64kv (V^T) chunks
  const int t = threadIdx.x, w = t >> 6, l = t & 63;
  const int quad = l >> 4, ln = l & 15;
  const int bid = blockIdx.x;
  const int qt = 15 - (bid >> 6);
  const int bh = bid & 63;
  const int h = bh & 15, b = bh >> 4;
  const int q0 = qt * 128;
  const int wq0 = q0 + w * 32;
  const unsigned short* Qh = Qn + ((size_t)(b * 16 + h)) * SEQ * 64;
  const unsigned short* Kg = Kn + ((size_t)(b * 4 + (h >> 2))) * SEQ * 64;
  const unsigned short* Vg = Vtg + ((size_t)(b * 4 + (h >> 2))) * 64 * SEQ;
  const int lrow = l >> 2;
  // pre-swizzled global 16B-slot within each 64B chunk-row (involution with read)
  const int lswz = (((l & 3) ^ ((lrow >> 1) & 3)) * 8);
  // swizzled read slot: LDS slot j holds global col j ^ ((row>>1)&3); row = ln
  const int qsw = (quad ^ ((ln >> 1) & 3)) << 4;

  bf16x8 aq[2][2];
#pragma unroll
  for (int mt = 0; mt < 2; ++mt)
#pragma unroll
    for (int ks = 0; ks < 2; ++ks)
      aq[mt][ks] = *(const bf16x8*)(Qh + (size_t)(wq0 + mt * 16 + ln) * 64 + ks * 32 + quad * 8);
  f32x4 o_acc[2][4] = {};
  f32x2 lp[2] = {};

  const float Cc  = 0.18033688011112042f;  // ASCALE * log2(e)
  const float B1c = -1.0436160e-6f;        // Cc * (-(ASCALE/CAP)^2 / 3)
  const float M2  = 11.541560327f;         // 8 * log2(e)
  const int qr0 = wq0 + ln;                // this lane's q row (within-mt base)

  const int jmax = 2 * qt + 2;

  // prologue: stage kv-tile 0 into buffer 0
#pragma unroll
  for (int i = 0; i < 2; ++i) {
    int s = w * 2 + i;
    int snt = s >> 1, sks = s & 1;
    async_copy16((char*)Ks[0] + s * 1024,
                 Kg + (size_t)(snt * 16 + lrow) * 64 + sks * 32 + lswz);
    async_copy16((char*)Vs[0] + s * 1024,
                 Vg + (size_t)(snt * 16 + lrow) * SEQ + sks * 32 + lswz);
  }

  for (int jj = 0; jj < jmax; ++jj) {
    const int kv0 = jj * 64;
    const int cur = jj & 1;
    // barrier: (a) drains this wave's outstanding global_load_lds (vmcnt) so
    // buf[cur] staged by prior iter is visible; (b) all waves' ds_reads of
    // buf[cur^1] from prior iter are done (lgkm drained) so restaging is safe.
    __syncthreads();
    if (jj + 1 < jmax) {
      const int kvn = kv0 + 64;
#pragma unroll
      for (int i = 0; i < 2; ++i) {
        int s = w * 2 + i;
        int snt = s >> 1, sks = s & 1;
        async_copy16((char*)Ks[cur ^ 1] + s * 1024,
                     Kg + (size_t)(kvn + snt * 16 + lrow) * 64 + sks * 32 + lswz);
        async_copy16((char*)Vs[cur ^ 1] + s * 1024,
                     Vg + (size_t)(snt * 16 + lrow) * SEQ + kvn + sks * 32 + lswz);
      }
    }
    if (kv0 > wq0 + 31) continue;   // wave fully above diagonal (no barrier below)

    // S^T = K Q^T (swapped operands): st[nt][mt] lane holds
    // P[q = mt*16+ln][kv = nt*16 + quad*4 + r]
    f32x4 st[4][2] = {};
    __builtin_amdgcn_s_setprio(1);
#pragma unroll
    for (int nt = 0; nt < 4; ++nt)
#pragma unroll
      for (int ks = 0; ks < 2; ++ks) {
        bf16x8 bk = *(const bf16x8*)((char*)Ks[cur] + (nt * 2 + ks) * 1024 + ln * 64 + qsw);
        st[nt][0] = __builtin_amdgcn_mfma_f32_16x16x32_bf16(bk, aq[0][ks], st[nt][0], 0, 0, 0);
        st[nt][1] = __builtin_amdgcn_mfma_f32_16x16x32_bf16(bk, aq[1][ks], st[nt][1], 0, 0, 0);
      }
    __builtin_amdgcn_s_setprio(0);

    const bool needMask = (kv0 + 63 > wq0);
    bf16x8 ap[2][2];
#pragma unroll
    for (int mt = 0; mt < 2; ++mt) {
      const int qrow = qr0 + mt * 16;
      unsigned Wp[4][2];
#pragma unroll
      for (int nt = 0; nt < 4; ++nt)
#pragma unroll
        for (int rp = 0; rp < 2; ++rp) {
          f32x2 s = { st[nt][mt][rp * 2], st[nt][mt][rp * 2 + 1] };
          f32x2 s2 = s * s;                       // v_pk_mul_f32
          f32x2 tt = s2 * B1c + Cc;               // v_pk_fma_f32
          f32x2 arg = s * tt - M2;                // v_pk_fma_f32
          float pr0 = fexp2(arg.x), pr1 = fexp2(arg.y);
          if (needMask) {
            const int kvb = kv0 + nt * 16 + quad * 4 + rp * 2;
            if (kvb > qrow)     pr0 = 0.0f;
            if (kvb + 1 > qrow) pr1 = 0.0f;
          }
          lp[mt] += (f32x2){pr0, pr1};            // v_pk_add_f32
          unsigned wpk;
          asm("v_cvt_pk_bf16_f32 %0, %1, %2" : "=v"(wpk) : "v"(pr0), "v"(pr1));
          Wp[nt][rp] = wpk;
        }
      // in-register transpose of kv ownership: [3:2]=quad -> [4:3]=quad
#pragma unroll
      for (int ks = 0; ks < 2; ++ks) {
        unsigned a0 = Wp[2 * ks][0], b0 = Wp[2 * ks + 1][0];
        unsigned a1 = Wp[2 * ks][1], b1 = Wp[2 * ks + 1][1];
        asm("v_permlane32_swap_b32 %0, %1" : "+v"(a0), "+v"(b0));
        asm("v_permlane16_swap_b32 %0, %1" : "+v"(a0), "+v"(b0));
        asm("v_permlane32_swap_b32 %0, %1" : "+v"(a1), "+v"(b1));
        asm("v_permlane16_swap_b32 %0, %1" : "+v"(a1), "+v"(b1));
        union { u32x4 u; bf16x8 bv; } cc;
        cc.u = (u32x4){a0, a1, b0, b1};
        ap[mt][ks] = cc.bv;
      }
    }

    // O += P V : each bv feeds both m-tiles
    __builtin_amdgcn_s_setprio(1);
#pragma unroll
    for (int nt = 0; nt < 4; ++nt)
#pragma unroll
      for (int ks = 0; ks < 2; ++ks) {
        bf16x8 bv = *(const bf16x8*)((char*)Vs[cur] + (nt * 2 + ks) * 1024 + ln * 64 + qsw);
        o_acc[0][nt] = __builtin_amdgcn_mfma_f32_16x16x32_bf16(ap[0][ks], bv, o_acc[0][nt], 0, 0, 0);
        o_acc[1][nt] = __builtin_amdgcn_mfma_f32_16x16x32_bf16(ap[1][ks], bv, o_acc[1][nt], 0, 0, 0);
      }
    __builtin_amdgcn_s_setprio(0);
  }

  // epilogue: row sums live per-lane at q=ln; reduce over quads, then
  // redistribute to the o_acc row owner (q = quad*4+r)
  float invl[2][4];
#pragma unroll
  for (int mt = 0; mt < 2; ++mt) {
    float s = lp[mt].x + lp[mt].y;
    s += __shfl_xor(s, 16, 64);
    s += __shfl_xor(s, 32, 64);
#pragma unroll
    for (int r = 0; r < 4; ++r)
      invl[mt][r] = __builtin_amdgcn_rcpf(__shfl(s, quad * 4 + r, 64));
  }
#pragma unroll
  for (int mt = 0; mt < 2; ++mt)
#pragma unroll
    for (int nt = 0; nt < 4; ++nt)
#pragma unroll
      for (int r = 0; r < 4; ++r) {
        int qrow = wq0 + mt * 16 + quad * 4 + r;
        int col = h * 64 + nt * 16 + ln;
        O[((size_t)(b * SEQ + qrow)) * 1024 + col] = f2bf_hup(o_acc[mt][nt][r] * invl[mt][r]);
      }
}

// ---------------- launch ----------------
extern "C" void kernel_launch(void* const* d_in, const int* in_sizes, int n_in,
                              void* d_out, int out_size, void* d_ws, size_t ws_size,
                              hipStream_t stream) {
  const float* x  = (const float*)d_in[0];
  const float* Wq = (const float*)d_in[1];
  const float* Wk = (const float*)d_in[2];
  const float* Wv = (const float*)d_in[3];
  const float* Wo = (const float*)d_in[4];
  const float* qw = (const float*)d_in[5];
  const float* kw = (const float*)d_in[6];
  float* out = (float*)d_out;

  char* ws = (char*)d_ws;
  unsigned short* xb   = (unsigned short*)(ws);                 // 16,777,216
  unsigned short* wqkv = (unsigned short*)(ws + 16777216);      //  3,145,728
  unsigned short* wo   = (unsigned short*)(ws + 19922944);      //  2,097,152
  unsigned short* Qn   = (unsigned short*)(ws + 22020096);      // 16,777,216
  unsigned short* Kn   = (unsigned short*)(ws + 38797312);      //  4,194,304
  unsigned short* Vtg  = (unsigned short*)(ws + 42991616);      //  4,194,304
  unsigned short* Ob   = (unsigned short*)(ws + 47185920);      // 16,777,216  -> ~64 MB

  cvt_all<<<10752, 256, 0, stream>>>(x, Wq, Wk, Wv, Wo, xb, wqkv, wo);
  gemm_qkv<<<dim3(MTOK / 128, NQKV / 128), 256, 0, stream>>>(xb, wqkv, qw, kw, Qn, Kn, Vtg);
  attn<<<1024, 256, 0, stream>>>(Qn, Kn, Vtg, Ob);
  gemm_bt_f32<<<dim3(MTOK / 128, 1024 / 128), 256, 0, stream>>>(Ob, wo, out, MTOK, 1024, 1024);
}